// Round 6
// baseline (93.478 us; speedup 1.0000x reference)
//
#include <hip/hip_runtime.h>
#include <math.h>
#include <float.h>

#define N 4096
#define D 256
#define NLAB 64
#define NT 32                      // 128-wide strips
#define NBLK (NT * (NT + 1) / 2)   // 528 upper-triangle tiles

static constexpr float INV_TEMP = 1.0f / 0.07f;
static constexpr float W_ORGAN = 2.0f;
static constexpr float W_FINE  = 4.0f;

typedef __bf16 bf16x8 __attribute__((ext_vector_type(8)));
typedef float  f32x4  __attribute__((ext_vector_type(4)));
typedef unsigned short u16;

typedef __attribute__((address_space(3))) char lds_char;
typedef __attribute__((address_space(1))) const char gbl_char;

__device__ __forceinline__ void decode_tri(int b, int& p, int& q)
{
    int rem = b, pp = 0;
    while (rem >= NT - pp) { rem -= NT - pp; ++pp; }
    p = pp; q = pp + rem;
}

// ---------------------------------------------------------------- bf16 split helpers
__device__ __forceinline__ u16 f2bf_rn(float x) {
    unsigned u = __float_as_uint(x);
    unsigned r = (u + 0x7fffu + ((u >> 16) & 1u)) >> 16;
    return (u16)r;
}
__device__ __forceinline__ float bf2f(u16 b) { return __uint_as_float(((unsigned)b) << 16); }

__global__ __launch_bounds__(256)
void ksplit(const float* __restrict__ F, u16* __restrict__ Fhi, u16* __restrict__ Flo)
{
    const int idx = blockIdx.x * 256 + threadIdx.x;
    float4 v = ((const float4*)F)[idx];
    ushort4 h, l;
    h.x = f2bf_rn(v.x); l.x = f2bf_rn(v.x - bf2f(h.x));
    h.y = f2bf_rn(v.y); l.y = f2bf_rn(v.y - bf2f(h.y));
    h.z = f2bf_rn(v.z); l.z = f2bf_rn(v.z - bf2f(h.z));
    h.w = f2bf_rn(v.w); l.w = f2bf_rn(v.w - bf2f(h.w));
    ((ushort4*)Fhi)[idx] = h;
    ((ushort4*)Flo)[idx] = l;
}

// ---------------------------------------------------------------- staging: global -> LDS (verified)
__device__ __forceinline__ void stage_chunk(const u16* __restrict__ Fhi, const u16* __restrict__ Flo,
                                            u16* sAh, u16* sAl, u16* sBh, u16* sBl,
                                            int i0, int j0, int kc, int t)
{
    const int w = t >> 6, lane = t & 63;
    #pragma unroll
    for (int i = 0; i < 2; ++i) {
        const int slotbase = w * 128 + i * 64;
        const int slot = slotbase + lane;
        const int row  = slot >> 2;
        const int k16  = (slot & 3) ^ (row & 3);
        const int ldsb = slotbase * 16;
        const size_t ga = (size_t)(i0 + row) * D + kc * 32 + k16 * 8;
        const size_t gb = (size_t)(j0 + row) * D + kc * 32 + k16 * 8;
        __builtin_amdgcn_global_load_lds((gbl_char*)(Fhi + ga), (lds_char*)((char*)sAh + ldsb), 16, 0, 0);
        __builtin_amdgcn_global_load_lds((gbl_char*)(Flo + ga), (lds_char*)((char*)sAl + ldsb), 16, 0, 0);
        __builtin_amdgcn_global_load_lds((gbl_char*)(Fhi + gb), (lds_char*)((char*)sBh + ldsb), 16, 0, 0);
        __builtin_amdgcn_global_load_lds((gbl_char*)(Flo + gb), (lds_char*)((char*)sBl + ldsb), 16, 0, 0);
    }
}

// ---------------------------------------------------------------- shared GEMM body (verified)
__device__ __forceinline__ void gemm_body(const u16* __restrict__ Fhi, const u16* __restrict__ Flo,
                                          u16* sAh, u16* sAl, u16* sBh, u16* sBl,
                                          int i0, int j0, int t, f32x4 acc[4][4])
{
    const int lane = t & 63, lr = lane & 15, lk = lane >> 4;
    const int wv = t >> 6, wr = wv >> 1, wc = wv & 1;

    int aoff[4], boff[4];
    #pragma unroll
    for (int m = 0; m < 4; ++m) {
        const int rowa = wr * 64 + m * 16 + lr;
        aoff[m] = rowa * 64 + ((lk ^ (rowa & 3)) << 4);
        const int rowb = wc * 64 + m * 16 + lr;
        boff[m] = rowb * 64 + ((lk ^ (rowb & 3)) << 4);
    }
    const f32x4 z = {0.f, 0.f, 0.f, 0.f};
    #pragma unroll
    for (int m = 0; m < 4; ++m)
        #pragma unroll
        for (int n = 0; n < 4; ++n) acc[m][n] = z;

    for (int kc = 0; kc < D / 32; ++kc) {
        __syncthreads();
        stage_chunk(Fhi, Flo, sAh, sAl, sBh, sBl, i0, j0, kc, t);
        __syncthreads();
        bf16x8 ah[4], al[4], bh[4], bl[4];
        #pragma unroll
        for (int m = 0; m < 4; ++m) {
            ah[m] = *(const bf16x8*)((const char*)sAh + aoff[m]);
            al[m] = *(const bf16x8*)((const char*)sAl + aoff[m]);
            bh[m] = *(const bf16x8*)((const char*)sBh + boff[m]);
            bl[m] = *(const bf16x8*)((const char*)sBl + boff[m]);
        }
        #pragma unroll
        for (int m = 0; m < 4; ++m)
            #pragma unroll
            for (int n = 0; n < 4; ++n) {
                acc[m][n] = __builtin_amdgcn_mfma_f32_16x16x32_bf16(ah[m], bh[n], acc[m][n], 0, 0, 0);
                acc[m][n] = __builtin_amdgcn_mfma_f32_16x16x32_bf16(ah[m], bl[n], acc[m][n], 0, 0, 0);
                acc[m][n] = __builtin_amdgcn_mfma_f32_16x16x32_bf16(al[m], bh[n], acc[m][n], 0, 0, 0);
            }
    }
}

// ---------------------------------------------------------------- upper-tri GEMM -> packed tile + max partials
// Mpart layout: [row][64]; row-max of tile (p,q) at chunk 2q+wc, col-max at chunk 2p+wr.
__global__ __launch_bounds__(256)
void kgemm_sym(const u16* __restrict__ Fhi, const u16* __restrict__ Flo,
               float* __restrict__ Spack, float* __restrict__ Mpart)
{
    __shared__ u16 smem[4][128 * 32];
    const int t = threadIdx.x;
    int p, q; decode_tri(blockIdx.x, p, q);
    const int i0 = p * 128, j0 = q * 128;

    f32x4 acc[4][4];
    gemm_body(Fhi, Flo, smem[0], smem[1], smem[2], smem[3], i0, j0, t, acc);

    const int lane = t & 63, lr = lane & 15, lk = lane >> 4;
    const int wv = t >> 6, wr = wv >> 1, wc = wv & 1;
    float* stile = Spack + (size_t)blockIdx.x * (128 * 128);

    const int qq = q * 2 + wc;
    #pragma unroll
    for (int m = 0; m < 4; ++m)
        #pragma unroll
        for (int r = 0; r < 4; ++r) {
            const int li = wr * 64 + m * 16 + lk * 4 + r;
            const int gi = i0 + li;
            float* srow = stile + li * 128 + wc * 64;
            float v = -FLT_MAX;
            #pragma unroll
            for (int n = 0; n < 4; ++n) {
                const int gj = j0 + wc * 64 + n * 16 + lr;
                float s = acc[m][n][r] * INV_TEMP;
                if (gi == gj) s = -1e9f;
                acc[m][n][r] = s;
                srow[n * 16 + lr] = s;
                v = fmaxf(v, s);
            }
            v = fmaxf(v, __shfl_xor(v, 1));
            v = fmaxf(v, __shfl_xor(v, 2));
            v = fmaxf(v, __shfl_xor(v, 4));
            v = fmaxf(v, __shfl_xor(v, 8));
            if (lr == 0) Mpart[(size_t)gi * 64 + qq] = v;
        }

    if (p != q) {
        #pragma unroll
        for (int n = 0; n < 4; ++n) {
            float cm = -FLT_MAX;
            #pragma unroll
            for (int m = 0; m < 4; ++m)
                #pragma unroll
                for (int r = 0; r < 4; ++r) cm = fmaxf(cm, acc[m][n][r]);
            cm = fmaxf(cm, __shfl_xor(cm, 16));
            cm = fmaxf(cm, __shfl_xor(cm, 32));
            if (lane < 16) {
                const int gj = j0 + wc * 64 + n * 16 + lane;
                Mpart[(size_t)gj * 64 + (p * 2 + wr)] = cm;
            }
        }
    }
}

// ---------------------------------------------------------------- reduce max
__global__ __launch_bounds__(256)
void kredmax(const float* __restrict__ Mpart, float* __restrict__ M)
{
    const int t = threadIdx.x, wv = t >> 6, lane = t & 63;
    const int row = blockIdx.x * 4 + wv;
    float v = Mpart[(size_t)row * 64 + lane];
    #pragma unroll
    for (int o = 1; o < 64; o <<= 1) v = fmaxf(v, __shfl_xor(v, o));
    if (lane == 0) M[row] = v;
}

// ---------------------------------------------------------------- both-orientation stats over packed tiles
// Row-partials [row][32]: tile (p,q) row-side -> chunk q; col-side (p<q) -> chunk p.
__global__ __launch_bounds__(256)
void kstats_sym(const float* __restrict__ Spack, const int* __restrict__ labels,
                const float* __restrict__ simtab, const float* __restrict__ M,
                float* __restrict__ DenP, float* __restrict__ WlgP,
                float* __restrict__ WsmP, float* __restrict__ CntP)
{
    __shared__ float Wtab[NLAB * NLAB];   // weight(sim[a][b]) at a*64+b
    __shared__ float WtabT[NLAB * NLAB];  // weight(sim[b][a]) at a*64+b
    __shared__ int   labP[128], labQ[128];
    __shared__ float Mp[128], Mq[128];
    __shared__ float colacc[4][4][128];   // [wave][stat][col]

    const int t = threadIdx.x;
    int p, q; decode_tri(blockIdx.x, p, q);
    const int i0 = p * 128, j0 = q * 128;

    for (int i = t; i < NLAB * NLAB; i += 256) {
        const int a = i >> 6, b = i & 63;
        const float s1 = simtab[i];
        Wtab[i]  = (s1 > 0.f && s1 < 1.f) ? s1 * W_FINE : ((s1 == 1.f) ? W_ORGAN : 0.f);
        const float s2 = simtab[b * NLAB + a];
        WtabT[i] = (s2 > 0.f && s2 < 1.f) ? s2 * W_FINE : ((s2 == 1.f) ? W_ORGAN : 0.f);
    }
    if (t < 128) {
        labP[t] = labels[i0 + t]; Mp[t] = M[i0 + t];
        labQ[t] = labels[j0 + t]; Mq[t] = M[j0 + t];
    }
    __syncthreads();

    const int wv = t >> 6, lane = t & 63;
    const bool diag = (p == q);
    const int c0 = 2 * lane, c1 = 2 * lane + 1;
    const int lb0 = labQ[c0], lb1 = labQ[c1];
    const float Mq0 = Mq[c0], Mq1 = Mq[c1];
    float cden0 = 0, cwlg0 = 0, cwsm0 = 0, ccnt0 = 0;
    float cden1 = 0, cwlg1 = 0, cwsm1 = 0, ccnt1 = 0;

    const float2* tile = (const float2*)(Spack + (size_t)blockIdx.x * (128 * 128));
    for (int rr = 0; rr < 32; ++rr) {
        const int li = wv * 32 + rr;
        const int gi = i0 + li;
        const int la = labP[li];
        const float Mi = Mp[li];
        const float wrow  = Wtab [la * NLAB + lane];
        const float wrowT = WtabT[la * NLAB + lane];
        const float2 sv = tile[li * 64 + lane];

        float w0 = __shfl(wrow, lb0);
        float w1 = __shfl(wrow, lb1);
        if (diag) { if (li == c0) w0 = 0.f; if (li == c1) w1 = 0.f; }
        const float l0 = fmaxf(sv.x - Mi, -50.f);
        const float l1 = fmaxf(sv.y - Mi, -50.f);
        float den = __expf(l0) + __expf(l1);
        float wlg = w0 * l0 + w1 * l1;
        float wsm = w0 + w1;
        float cnt = (w0 > 0.f ? 1.f : 0.f) + (w1 > 0.f ? 1.f : 0.f);
        #pragma unroll
        for (int o = 1; o < 64; o <<= 1) {
            den += __shfl_xor(den, o);
            wlg += __shfl_xor(wlg, o);
            wsm += __shfl_xor(wsm, o);
            cnt += __shfl_xor(cnt, o);
        }
        if (lane == 0) {
            DenP[(size_t)gi * 32 + q] = den;
            WlgP[(size_t)gi * 32 + q] = wlg;
            WsmP[(size_t)gi * 32 + q] = wsm;
            CntP[(size_t)gi * 32 + q] = cnt;
        }
        if (!diag) {
            const float lw0 = __shfl(wrowT, lb0);
            const float lw1 = __shfl(wrowT, lb1);
            const float m0 = fmaxf(sv.x - Mq0, -50.f);
            const float m1 = fmaxf(sv.y - Mq1, -50.f);
            cden0 += __expf(m0); cwlg0 += lw0 * m0; cwsm0 += lw0; ccnt0 += (lw0 > 0.f ? 1.f : 0.f);
            cden1 += __expf(m1); cwlg1 += lw1 * m1; cwsm1 += lw1; ccnt1 += (lw1 > 0.f ? 1.f : 0.f);
        }
    }
    if (!diag) {
        colacc[wv][0][c0] = cden0; colacc[wv][1][c0] = cwlg0; colacc[wv][2][c0] = cwsm0; colacc[wv][3][c0] = ccnt0;
        colacc[wv][0][c1] = cden1; colacc[wv][1][c1] = cwlg1; colacc[wv][2][c1] = cwsm1; colacc[wv][3][c1] = ccnt1;
        __syncthreads();
        if (t < 128) {
            const int gj = j0 + t;
            const float d = colacc[0][0][t] + colacc[1][0][t] + colacc[2][0][t] + colacc[3][0][t];
            const float g = colacc[0][1][t] + colacc[1][1][t] + colacc[2][1][t] + colacc[3][1][t];
            const float w = colacc[0][2][t] + colacc[1][2][t] + colacc[2][2][t] + colacc[3][2][t];
            const float c = colacc[0][3][t] + colacc[1][3][t] + colacc[2][3][t] + colacc[3][3][t];
            DenP[(size_t)gj * 32 + p] = d;
            WlgP[(size_t)gj * 32 + p] = g;
            WsmP[(size_t)gj * 32 + p] = w;
            CntP[(size_t)gj * 32 + p] = c;
        }
    }
}

// ---------------------------------------------------------------- per-row combine
__global__ __launch_bounds__(256)
void krow(const float* __restrict__ DenP, const float* __restrict__ WlgP,
          const float* __restrict__ WsmP, const float* __restrict__ CntP,
          float* __restrict__ Mlp, float* __restrict__ Hp)
{
    const int t = threadIdx.x, wv = t >> 6, lane = t & 63;
    const int row = blockIdx.x * 4 + wv;
    float den = 0, wlg = 0, wsm = 0, cnt = 0;
    if (lane < 32) {
        den = DenP[(size_t)row * 32 + lane];
        wlg = WlgP[(size_t)row * 32 + lane];
        wsm = WsmP[(size_t)row * 32 + lane];
        cnt = CntP[(size_t)row * 32 + lane];
    }
    #pragma unroll
    for (int o = 1; o < 32; o <<= 1) {
        den += __shfl_xor(den, o);
        wlg += __shfl_xor(wlg, o);
        wsm += __shfl_xor(wsm, o);
        cnt += __shfl_xor(cnt, o);
    }
    if (lane == 0) {
        const float logden = logf(den + 1e-8f);
        const float mlp = (wlg - logden * wsm) / fmaxf(wsm, 1e-8f);
        Mlp[row] = (cnt > 0.f) ? mlp : 0.f;
        Hp[row]  = (cnt > 0.f) ? 1.f : 0.f;
    }
}

// ---------------------------------------------------------------- final reduce
__global__ __launch_bounds__(256)
void kfinal(const float* __restrict__ Mlp, const float* __restrict__ Hp, float* __restrict__ out)
{
    const int t = threadIdx.x;
    float ls = 0.f, np = 0.f;
    for (int i = t; i < N; i += 256) { ls += Mlp[i]; np += Hp[i]; }
    #pragma unroll
    for (int o = 32; o; o >>= 1) {
        ls += __shfl_down(ls, o);
        np += __shfl_down(np, o);
    }
    __shared__ float s1[4], s2[4];
    const int wid = t >> 6;
    if ((t & 63) == 0) { s1[wid] = ls; s2[wid] = np; }
    __syncthreads();
    if (t == 0) {
        const float L = s1[0] + s1[1] + s1[2] + s1[3];
        const float P = s2[0] + s2[1] + s2[2] + s2[3];
        out[0] = -L / fmaxf(P, 1.0f);
    }
}

// ---------------------------------------------------------------- launch
extern "C" void kernel_launch(void* const* d_in, const int* in_sizes, int n_in,
                              void* d_out, int out_size, void* d_ws, size_t ws_size,
                              hipStream_t stream)
{
    (void)in_sizes; (void)n_in; (void)out_size; (void)ws_size;
    const float* F      = (const float*)d_in[0];
    const int*   labels = (const int*)d_in[1];
    const float* simtab = (const float*)d_in[2];
    float* out = (float*)d_out;

    u16* Fhi = (u16*)d_ws;                          // N*D u16
    u16* Flo = Fhi + (size_t)N * D;
    float* Spack = (float*)(Flo + (size_t)N * D);   // NBLK * 16384 f32 (~34 MB)
    float* Mpart = Spack + (size_t)NBLK * 128 * 128; // N*64
    float* M     = Mpart + (size_t)N * 64;          // N
    float* DenP  = M + N;                           // N*32 each
    float* WlgP  = DenP + (size_t)N * 32;
    float* WsmP  = WlgP + (size_t)N * 32;
    float* CntP  = WsmP + (size_t)N * 32;
    float* Mlp   = CntP + (size_t)N * 32;           // N
    float* Hp    = Mlp + N;                         // N

    ksplit<<<(N * D) / (256 * 4), 256, 0, stream>>>(F, Fhi, Flo);
    kgemm_sym<<<NBLK, 256, 0, stream>>>(Fhi, Flo, Spack, Mpart);
    kredmax<<<N / 4, 256, 0, stream>>>(Mpart, M);
    kstats_sym<<<NBLK, 256, 0, stream>>>(Spack, labels, simtab, M, DenP, WlgP, WsmP, CntP);
    krow<<<N / 4, 256, 0, stream>>>(DenP, WlgP, WsmP, CntP, Mlp, Hp);
    kfinal<<<1, 256, 0, stream>>>(Mlp, Hp, out);
}

// Round 7
// 79.358 us; speedup vs baseline: 1.1779x; 1.1779x over previous
//
#include <hip/hip_runtime.h>
#include <math.h>
#include <float.h>

#define N 4096
#define D 256
#define NLAB 64
#define NT 32                      // 128-wide strips
#define NBLK (NT * (NT + 1) / 2)   // 528 upper-triangle tiles

static constexpr float INV_TEMP = 1.0f / 0.07f;
static constexpr float W_ORGAN = 2.0f;
static constexpr float W_FINE  = 4.0f;

typedef __bf16 bf16x8 __attribute__((ext_vector_type(8)));
typedef float  f32x4  __attribute__((ext_vector_type(4)));
typedef unsigned short u16;

typedef __attribute__((address_space(3))) char lds_char;
typedef __attribute__((address_space(1))) const char gbl_char;

__device__ __forceinline__ void decode_tri(int b, int& p, int& q)
{
    int rem = b, pp = 0;
    while (rem >= NT - pp) { rem -= NT - pp; ++pp; }
    p = pp; q = pp + rem;
}

// ---------------------------------------------------------------- bf16 split helpers
__device__ __forceinline__ u16 f2bf_rn(float x) {
    unsigned u = __float_as_uint(x);
    unsigned r = (u + 0x7fffu + ((u >> 16) & 1u)) >> 16;
    return (u16)r;
}
__device__ __forceinline__ float bf2f(u16 b) { return __uint_as_float(((unsigned)b) << 16); }

__global__ __launch_bounds__(256)
void ksplit(const float* __restrict__ F, u16* __restrict__ Fhi, u16* __restrict__ Flo)
{
    const int idx = blockIdx.x * 256 + threadIdx.x;
    float4 v = ((const float4*)F)[idx];
    ushort4 h, l;
    h.x = f2bf_rn(v.x); l.x = f2bf_rn(v.x - bf2f(h.x));
    h.y = f2bf_rn(v.y); l.y = f2bf_rn(v.y - bf2f(h.y));
    h.z = f2bf_rn(v.z); l.z = f2bf_rn(v.z - bf2f(h.z));
    h.w = f2bf_rn(v.w); l.w = f2bf_rn(v.w - bf2f(h.w));
    ((ushort4*)Fhi)[idx] = h;
    ((ushort4*)Flo)[idx] = l;
}

// ---------------------------------------------------------------- staging: global -> LDS (verified)
__device__ __forceinline__ void stage_chunk(const u16* __restrict__ Fhi, const u16* __restrict__ Flo,
                                            u16* sAh, u16* sAl, u16* sBh, u16* sBl,
                                            int i0, int j0, int kc, int t)
{
    const int w = t >> 6, lane = t & 63;
    #pragma unroll
    for (int i = 0; i < 2; ++i) {
        const int slotbase = w * 128 + i * 64;
        const int slot = slotbase + lane;
        const int row  = slot >> 2;
        const int k16  = (slot & 3) ^ (row & 3);
        const int ldsb = slotbase * 16;
        const size_t ga = (size_t)(i0 + row) * D + kc * 32 + k16 * 8;
        const size_t gb = (size_t)(j0 + row) * D + kc * 32 + k16 * 8;
        __builtin_amdgcn_global_load_lds((gbl_char*)(Fhi + ga), (lds_char*)((char*)sAh + ldsb), 16, 0, 0);
        __builtin_amdgcn_global_load_lds((gbl_char*)(Flo + ga), (lds_char*)((char*)sAl + ldsb), 16, 0, 0);
        __builtin_amdgcn_global_load_lds((gbl_char*)(Fhi + gb), (lds_char*)((char*)sBh + ldsb), 16, 0, 0);
        __builtin_amdgcn_global_load_lds((gbl_char*)(Flo + gb), (lds_char*)((char*)sBl + ldsb), 16, 0, 0);
    }
}

// ---------------------------------------------------------------- shared GEMM body (verified)
__device__ __forceinline__ void gemm_body(const u16* __restrict__ Fhi, const u16* __restrict__ Flo,
                                          u16* sAh, u16* sAl, u16* sBh, u16* sBl,
                                          int i0, int j0, int t, f32x4 acc[4][4])
{
    const int lane = t & 63, lr = lane & 15, lk = lane >> 4;
    const int wv = t >> 6, wr = wv >> 1, wc = wv & 1;

    int aoff[4], boff[4];
    #pragma unroll
    for (int m = 0; m < 4; ++m) {
        const int rowa = wr * 64 + m * 16 + lr;
        aoff[m] = rowa * 64 + ((lk ^ (rowa & 3)) << 4);
        const int rowb = wc * 64 + m * 16 + lr;
        boff[m] = rowb * 64 + ((lk ^ (rowb & 3)) << 4);
    }
    const f32x4 z = {0.f, 0.f, 0.f, 0.f};
    #pragma unroll
    for (int m = 0; m < 4; ++m)
        #pragma unroll
        for (int n = 0; n < 4; ++n) acc[m][n] = z;

    for (int kc = 0; kc < D / 32; ++kc) {
        __syncthreads();
        stage_chunk(Fhi, Flo, sAh, sAl, sBh, sBl, i0, j0, kc, t);
        __syncthreads();
        bf16x8 ah[4], al[4], bh[4], bl[4];
        #pragma unroll
        for (int m = 0; m < 4; ++m) {
            ah[m] = *(const bf16x8*)((const char*)sAh + aoff[m]);
            al[m] = *(const bf16x8*)((const char*)sAl + aoff[m]);
            bh[m] = *(const bf16x8*)((const char*)sBh + boff[m]);
            bl[m] = *(const bf16x8*)((const char*)sBl + boff[m]);
        }
        #pragma unroll
        for (int m = 0; m < 4; ++m)
            #pragma unroll
            for (int n = 0; n < 4; ++n) {
                acc[m][n] = __builtin_amdgcn_mfma_f32_16x16x32_bf16(ah[m], bh[n], acc[m][n], 0, 0, 0);
                acc[m][n] = __builtin_amdgcn_mfma_f32_16x16x32_bf16(ah[m], bl[n], acc[m][n], 0, 0, 0);
                acc[m][n] = __builtin_amdgcn_mfma_f32_16x16x32_bf16(al[m], bh[n], acc[m][n], 0, 0, 0);
            }
    }
}

// ---------------------------------------------------------------- upper-tri GEMM -> packed tile + max partials (verified)
__global__ __launch_bounds__(256)
void kgemm_sym(const u16* __restrict__ Fhi, const u16* __restrict__ Flo,
               float* __restrict__ Spack, float* __restrict__ Mpart)
{
    __shared__ u16 smem[4][128 * 32];
    const int t = threadIdx.x;
    int p, q; decode_tri(blockIdx.x, p, q);
    const int i0 = p * 128, j0 = q * 128;

    f32x4 acc[4][4];
    gemm_body(Fhi, Flo, smem[0], smem[1], smem[2], smem[3], i0, j0, t, acc);

    const int lane = t & 63, lr = lane & 15, lk = lane >> 4;
    const int wv = t >> 6, wr = wv >> 1, wc = wv & 1;
    float* stile = Spack + (size_t)blockIdx.x * (128 * 128);

    const int qq = q * 2 + wc;
    #pragma unroll
    for (int m = 0; m < 4; ++m)
        #pragma unroll
        for (int r = 0; r < 4; ++r) {
            const int li = wr * 64 + m * 16 + lk * 4 + r;
            const int gi = i0 + li;
            float* srow = stile + li * 128 + wc * 64;
            float v = -FLT_MAX;
            #pragma unroll
            for (int n = 0; n < 4; ++n) {
                const int gj = j0 + wc * 64 + n * 16 + lr;
                float s = acc[m][n][r] * INV_TEMP;
                if (gi == gj) s = -1e9f;
                acc[m][n][r] = s;
                srow[n * 16 + lr] = s;
                v = fmaxf(v, s);
            }
            v = fmaxf(v, __shfl_xor(v, 1));
            v = fmaxf(v, __shfl_xor(v, 2));
            v = fmaxf(v, __shfl_xor(v, 4));
            v = fmaxf(v, __shfl_xor(v, 8));
            if (lr == 0) Mpart[(size_t)gi * 64 + qq] = v;
        }

    if (p != q) {
        #pragma unroll
        for (int n = 0; n < 4; ++n) {
            float cm = -FLT_MAX;
            #pragma unroll
            for (int m = 0; m < 4; ++m)
                #pragma unroll
                for (int r = 0; r < 4; ++r) cm = fmaxf(cm, acc[m][n][r]);
            cm = fmaxf(cm, __shfl_xor(cm, 16));
            cm = fmaxf(cm, __shfl_xor(cm, 32));
            if (lane < 16) {
                const int gj = j0 + wc * 64 + n * 16 + lane;
                Mpart[(size_t)gj * 64 + (p * 2 + wr)] = cm;
            }
        }
    }
}

// ---------------------------------------------------------------- reduce max (verified)
__global__ __launch_bounds__(256)
void kredmax(const float* __restrict__ Mpart, float* __restrict__ M)
{
    const int t = threadIdx.x, wv = t >> 6, lane = t & 63;
    const int row = blockIdx.x * 4 + wv;
    float v = Mpart[(size_t)row * 64 + lane];
    #pragma unroll
    for (int o = 1; o < 64; o <<= 1) v = fmaxf(v, __shfl_xor(v, o));
    if (lane == 0) M[row] = v;
}

// ---------------------------------------------------------------- LDS-tile two-pass stats (row + mirrored col)
// Partials [row][32]: tile (p,q) row-side -> chunk q; col-side (p<q) -> chunk p.
__global__ __launch_bounds__(256)
void kstats2(const float* __restrict__ Spack, const int* __restrict__ labels,
             const float* __restrict__ simtab, const float* __restrict__ M,
             float* __restrict__ DenP, float* __restrict__ WlgP,
             float* __restrict__ WsmP, float* __restrict__ CntP)
{
    __shared__ float tile[128 * 129];      // first 64*65 floats double as padded sim during init
    __shared__ u16   WtabT[NLAB * NLAB];   // WtabT[b*64+a] = weight(sim[a][b]) * 16383, u16
    __shared__ int   labP_s[128], labQ_s[128];

    const int t = threadIdx.x;
    int p, q; decode_tri(blockIdx.x, p, q);
    const int i0 = p * 128, j0 = q * 128;
    const bool diag = (p == q);

    // --- build transposed weight table via padded-LDS sim transpose
    float* simPad = tile;                               // [64][65]
    for (int i = t; i < NLAB * NLAB; i += 256)
        simPad[(i >> 6) * 65 + (i & 63)] = simtab[i];
    if (t < 128) { labP_s[t] = labels[i0 + t]; labQ_s[t] = labels[j0 + t]; }
    __syncthreads();
    for (int i = t; i < NLAB * NLAB; i += 256) {
        const int b = i >> 6, a = i & 63;               // transposed read: spread banks via pad
        const float s = simPad[a * 65 + b];
        const float w = (s > 0.f && s < 1.f) ? s * W_FINE : ((s == 1.f) ? W_ORGAN : 0.f);
        WtabT[b * NLAB + a] = (u16)__float2int_rn(w * 16383.0f);
    }
    __syncthreads();

    // --- stage tile (row stride 129 floats: pad kills bank conflicts in both passes)
    const float4* src = (const float4*)(Spack + (size_t)blockIdx.x * (128 * 128));
    #pragma unroll
    for (int it = 0; it < 16; ++it) {
        const int idx4 = it * 256 + t;
        const int row = idx4 >> 5;
        const int cb  = (idx4 & 31) * 4;
        const float4 v = src[idx4];
        float* dst = &tile[row * 129 + cb];
        dst[0] = v.x; dst[1] = v.y; dst[2] = v.z; dst[3] = v.w;
    }
    __syncthreads();

    // --- row pass: thread -> (row = t>>1, half h = t&1), 64 cols each
    {
        const int row = t >> 1, h = t & 1;
        const int gi = i0 + row;
        const int la = labP_s[row];
        const float Mi = M[gi];
        const float* trow = &tile[row * 129 + h * 64];
        float den = 0.f, wlg = 0.f, wsm = 0.f, cnt = 0.f;
        #pragma unroll 8
        for (int c = 0; c < 64; ++c) {
            const int col = h * 64 + c;
            const float sval = trow[c];
            int uw = WtabT[labQ_s[col] * NLAB + la];
            if (diag && col == row) uw = 0;
            const float w = (float)uw * (1.0f / 16383.0f);
            const float logit = fmaxf(sval - Mi, -50.f);
            den += __expf(logit);
            wlg += w * logit;
            wsm += w;
            cnt += (uw > 0) ? 1.f : 0.f;
        }
        den += __shfl_xor(den, 1);
        wlg += __shfl_xor(wlg, 1);
        wsm += __shfl_xor(wsm, 1);
        cnt += __shfl_xor(cnt, 1);
        if (h == 0) {
            DenP[(size_t)gi * 32 + q] = den;
            WlgP[(size_t)gi * 32 + q] = wlg;
            WsmP[(size_t)gi * 32 + q] = wsm;
            CntP[(size_t)gi * 32 + q] = cnt;
        }
    }

    // --- col pass (mirror orientation), skipped on diagonal tiles
    if (!diag) {
        const int col = t >> 1, h = t & 1;
        const int gj = j0 + col;
        const int laq = labQ_s[col];
        const float Mj = M[gj];
        float den = 0.f, wlg = 0.f, wsm = 0.f, cnt = 0.f;
        #pragma unroll 8
        for (int rr = 0; rr < 64; ++rr) {
            const int row = h * 64 + rr;
            const float sval = tile[row * 129 + col];
            const int uw = WtabT[labP_s[row] * NLAB + laq];
            const float w = (float)uw * (1.0f / 16383.0f);
            const float logit = fmaxf(sval - Mj, -50.f);
            den += __expf(logit);
            wlg += w * logit;
            wsm += w;
            cnt += (uw > 0) ? 1.f : 0.f;
        }
        den += __shfl_xor(den, 1);
        wlg += __shfl_xor(wlg, 1);
        wsm += __shfl_xor(wsm, 1);
        cnt += __shfl_xor(cnt, 1);
        if (h == 0) {
            DenP[(size_t)gj * 32 + p] = den;
            WlgP[(size_t)gj * 32 + p] = wlg;
            WsmP[(size_t)gj * 32 + p] = wsm;
            CntP[(size_t)gj * 32 + p] = cnt;
        }
    }
}

// ---------------------------------------------------------------- per-row combine (verified)
__global__ __launch_bounds__(256)
void krow(const float* __restrict__ DenP, const float* __restrict__ WlgP,
          const float* __restrict__ WsmP, const float* __restrict__ CntP,
          float* __restrict__ Mlp, float* __restrict__ Hp)
{
    const int t = threadIdx.x, wv = t >> 6, lane = t & 63;
    const int row = blockIdx.x * 4 + wv;
    float den = 0, wlg = 0, wsm = 0, cnt = 0;
    if (lane < 32) {
        den = DenP[(size_t)row * 32 + lane];
        wlg = WlgP[(size_t)row * 32 + lane];
        wsm = WsmP[(size_t)row * 32 + lane];
        cnt = CntP[(size_t)row * 32 + lane];
    }
    #pragma unroll
    for (int o = 1; o < 32; o <<= 1) {
        den += __shfl_xor(den, o);
        wlg += __shfl_xor(wlg, o);
        wsm += __shfl_xor(wsm, o);
        cnt += __shfl_xor(cnt, o);
    }
    if (lane == 0) {
        const float logden = logf(den + 1e-8f);
        const float mlp = (wlg - logden * wsm) / fmaxf(wsm, 1e-8f);
        Mlp[row] = (cnt > 0.f) ? mlp : 0.f;
        Hp[row]  = (cnt > 0.f) ? 1.f : 0.f;
    }
}

// ---------------------------------------------------------------- final reduce (verified)
__global__ __launch_bounds__(256)
void kfinal(const float* __restrict__ Mlp, const float* __restrict__ Hp, float* __restrict__ out)
{
    const int t = threadIdx.x;
    float ls = 0.f, np = 0.f;
    for (int i = t; i < N; i += 256) { ls += Mlp[i]; np += Hp[i]; }
    #pragma unroll
    for (int o = 32; o; o >>= 1) {
        ls += __shfl_down(ls, o);
        np += __shfl_down(np, o);
    }
    __shared__ float s1[4], s2[4];
    const int wid = t >> 6;
    if ((t & 63) == 0) { s1[wid] = ls; s2[wid] = np; }
    __syncthreads();
    if (t == 0) {
        const float L = s1[0] + s1[1] + s1[2] + s1[3];
        const float P = s2[0] + s2[1] + s2[2] + s2[3];
        out[0] = -L / fmaxf(P, 1.0f);
    }
}

// ---------------------------------------------------------------- launch
extern "C" void kernel_launch(void* const* d_in, const int* in_sizes, int n_in,
                              void* d_out, int out_size, void* d_ws, size_t ws_size,
                              hipStream_t stream)
{
    (void)in_sizes; (void)n_in; (void)out_size; (void)ws_size;
    const float* F      = (const float*)d_in[0];
    const int*   labels = (const int*)d_in[1];
    const float* simtab = (const float*)d_in[2];
    float* out = (float*)d_out;

    u16* Fhi = (u16*)d_ws;                           // N*D u16
    u16* Flo = Fhi + (size_t)N * D;
    float* Spack = (float*)(Flo + (size_t)N * D);    // NBLK * 16384 f32 (~34 MB)
    float* Mpart = Spack + (size_t)NBLK * 128 * 128; // N*64
    float* M     = Mpart + (size_t)N * 64;           // N
    float* DenP  = M + N;                            // N*32 each
    float* WlgP  = DenP + (size_t)N * 32;
    float* WsmP  = WlgP + (size_t)N * 32;
    float* CntP  = WsmP + (size_t)N * 32;
    float* Mlp   = CntP + (size_t)N * 32;            // N
    float* Hp    = Mlp + N;                          // N

    ksplit<<<(N * D) / (256 * 4), 256, 0, stream>>>(F, Fhi, Flo);
    kgemm_sym<<<NBLK, 256, 0, stream>>>(Fhi, Flo, Spack, Mpart);
    kredmax<<<N / 4, 256, 0, stream>>>(Mpart, M);
    kstats2<<<NBLK, 256, 0, stream>>>(Spack, labels, simtab, M, DenP, WlgP, WsmP, CntP);
    krow<<<N / 4, 256, 0, stream>>>(DenP, WlgP, WsmP, CntP, Mlp, Hp);
    kfinal<<<1, 256, 0, stream>>>(Mlp, Hp, out);
}